// Round 8
// baseline (181.662 us; speedup 1.0000x reference)
//
#include <hip/hip_runtime.h>
#include <math.h>

// N_AGENTS=16, RNN_H=64, N_HEADS=4, GAT_D=32, EMB=32, SDIM=128, B=4096 rows

typedef __attribute__((ext_vector_type(8))) short short8;
typedef __attribute__((ext_vector_type(8))) unsigned short ushort8;
typedef __attribute__((ext_vector_type(4))) unsigned short ushort4v;
typedef __attribute__((ext_vector_type(4))) float float4v;
typedef __attribute__((ext_vector_type(4))) _Float16 half4v;

static __device__ inline unsigned short f2bf(float f) {
    unsigned int x;
    __builtin_memcpy(&x, &f, 4);
    unsigned int r = x + 0x7fffu + ((x >> 16) & 1u);   // RNE
    return (unsigned short)(r >> 16);
}

static __device__ inline short8 pack8(float4 f0, float4 f1) {
    ushort8 o;
    o[0] = f2bf(f0.x); o[1] = f2bf(f0.y); o[2] = f2bf(f0.z); o[3] = f2bf(f0.w);
    o[4] = f2bf(f1.x); o[5] = f2bf(f1.y); o[6] = f2bf(f1.z); o[7] = f2bf(f1.w);
    short8 s;
    __builtin_memcpy(&s, &o, 16);
    return s;
}

// ---------------------------------------------------------------------------
// K0: prep. blocks 0..255: w1sT 16-col transpose tiles; 256: WgT (144 cols:
// 128 W_gat^T + 4 src-proj + 4 dst-proj + 8 zero); 257: WsT.
// ---------------------------------------------------------------------------
__global__ __launch_bounds__(256) void k0_prep(
    const float* __restrict__ w1s_W,     // [129][4096]
    const float* __restrict__ W_gat,     // [64][128]
    const float* __restrict__ att_a,     // [4][64]
    const float* __restrict__ b1_W,      // [128][32]
    const float* __restrict__ wf_W,      // [128][32]
    const float* __restrict__ V1_W,      // [128][32]
    unsigned short* __restrict__ w1sT,   // [4096 cols][128 k] bf16
    unsigned short* __restrict__ WgT,    // [144 cols][64 k] bf16
    float* __restrict__ WsT)             // [96][128] fp32 (b1|wf|V1 transposed)
{
    __shared__ __align__(16) unsigned short T[128 * 72];  // 18KB, reused
    const int tid = threadIdx.x, bx = blockIdx.x;
    if (bx < 256) {
        const int c0 = bx * 16;
        const int cc = tid & 15, kr = tid >> 4;
        #pragma unroll
        for (int t = 0; t < 8; ++t) {
            int k = t * 16 + kr;
            T[cc * 136 + k] = f2bf(w1s_W[(size_t)k * 4096 + c0 + cc]);
        }
        __syncthreads();
        const int col = tid >> 4, seg = tid & 15;
        *(ushort8*)&w1sT[(size_t)(c0 + col) * 128 + seg * 8] =
            *(const ushort8*)&T[col * 136 + seg * 8];
    } else if (bx == 256) {
        #pragma unroll
        for (int t = 0; t < 32; ++t) {
            int i = t * 256 + tid;
            int k = i >> 7, c = i & 127;
            T[c * 72 + k] = f2bf(W_gat[k * 128 + c]);
        }
        __syncthreads();
        #pragma unroll
        for (int t = 0; t < 4; ++t) {
            int i = t * 256 + tid;
            int c = i >> 3, seg = i & 7;
            *(ushort8*)&WgT[c * 64 + seg * 8] = *(const ushort8*)&T[c * 72 + seg * 8];
        }
        // fused attention projections: cols 128+h = src-h, 132+h = dst-h
        {
            const int k = tid >> 2, h = tid & 3;
            float ss = 0.f, dd = 0.f;
            #pragma unroll
            for (int d = 0; d < 32; ++d) {
                float wv = W_gat[k * 128 + h * 32 + d];
                ss = fmaf(wv, att_a[h * 64 + d], ss);
                dd = fmaf(wv, att_a[h * 64 + 32 + d], dd);
            }
            WgT[(128 + h) * 64 + k] = f2bf(ss);
            WgT[(132 + h) * 64 + k] = f2bf(dd);
            WgT[(136 + h) * 64 + k] = 0;
            WgT[(140 + h) * 64 + k] = 0;
        }
    } else {
        for (int i = tid; i < 12288; i += 256) {
            int row = i >> 7, k = i & 127;
            int set = row >> 5, e = row & 31;
            const float* Wm = (set == 0) ? b1_W : ((set == 1) ? wf_W : V1_W);
            WsT[(size_t)row * 128 + k] = Wm[k * 32 + e];
        }
    }
}

// ---------------------------------------------------------------------------
// K1: GAT. 2 waves per batch row (wave = head-pair): block = 2 rows x 2
// halves; grid 2048 x 256 = 8192 waves (32/CU). Each wave: 5 MFMA tiles
// (its 2 heads' hp + proj), LDS scratch for src/dst routing, softmax,
// f16 MFMA2, g store; half 0 does b1/wf GEMVs, half 1 does V1->v and
// seeds out[row] = v.
// ---------------------------------------------------------------------------
__global__ __launch_bounds__(256) void k1_gat(
    const float* __restrict__ hidden_states,  // [4096*16][64] fp32
    const unsigned short* __restrict__ WgT,   // [144][64] bf16
    const float* __restrict__ states,
    const float* __restrict__ WsT,            // [96][128] fp32
    const float* __restrict__ b1_b, const float* __restrict__ wf_b,
    const float* __restrict__ V1_b, const float* __restrict__ V2_W,
    const float* __restrict__ V2_b,
    unsigned short* __restrict__ g_bf,        // [B][4][16][32] bf16
    float* __restrict__ b1v, float* __restrict__ wfv,
    float* __restrict__ out)                  // seeded with v term
{
    const int wave = threadIdx.x >> 6;
    const int b = blockIdx.x * 2 + (wave >> 1);
    const int half = wave & 1;
    const int lane = threadIdx.x & 63, m = lane & 15, quad = lane >> 4;
    __shared__ __align__(16) float sc[4 * 320];   // per-wave scratch, 5KB
    float* scr = &sc[wave * 320];

    // ---- MFMA1: this half's 4 hp tiles + proj tile ----
    const float* hrow = hidden_states + ((size_t)b * 16 + m) * 64;
    float4 f0 = *(const float4*)(hrow + quad * 8);
    float4 f1 = *(const float4*)(hrow + quad * 8 + 4);
    short8 a0 = pack8(f0, f1);
    f0 = *(const float4*)(hrow + 32 + quad * 8);
    f1 = *(const float4*)(hrow + 32 + quad * 8 + 4);
    short8 a1 = pack8(f0, f1);

    float4v hpt[4], hptP;
    #pragma unroll
    for (int t = 0; t < 5; ++t) {
        const int nt = (t < 4) ? (half * 4 + t) : 8;
        const int c = nt * 16 + m;
        short8 bf0 = *(const short8*)&WgT[c * 64 + quad * 8];
        short8 bf1 = *(const short8*)&WgT[c * 64 + 32 + quad * 8];
        float4v z = (float4v){0.f, 0.f, 0.f, 0.f};
        z = __builtin_amdgcn_mfma_f32_16x16x32_bf16(a0, bf0, z, 0, 0, 0);
        z = __builtin_amdgcn_mfma_f32_16x16x32_bf16(a1, bf1, z, 0, 0, 0);
        if (t < 4) hpt[t] = z; else hptP = z;
    }

    // stash proj tile transposed: scr[col*20 + row]
    {
        float4 pr = {hptP[0], hptP[1], hptP[2], hptP[3]};
        *(float4*)&scr[m * 20 + quad * 4] = pr;
    }

    // ---- this half's 2 heads: softmax + MFMA2 ----
    #pragma unroll
    for (int hh = 0; hh < 2; ++hh) {
        const int h = half * 2 + hh;
        const float src_m = scr[h * 20 + m];                        // src[i=m]
        float4 pdv = *(const float4*)&scr[(4 + h) * 20 + quad * 4]; // dst[j]
        float pd[4] = {pdv.x, pdv.y, pdv.z, pdv.w};

        float e_[4];
        #pragma unroll
        for (int jj = 0; jj < 4; ++jj) {
            float x = src_m + pd[jj];
            e_[jj] = fmaxf(x, 0.2f * x);       // leaky_relu(0.2)
        }
        float mx = fmaxf(fmaxf(e_[0], e_[1]), fmaxf(e_[2], e_[3]));
        mx = fmaxf(mx, __shfl_xor(mx, 16));
        mx = fmaxf(mx, __shfl_xor(mx, 32));
        float p_[4], ssum = 0.f;
        #pragma unroll
        for (int jj = 0; jj < 4; ++jj) { p_[jj] = __expf(e_[jj] - mx); ssum += p_[jj]; }
        ssum += __shfl_xor(ssum, 16);
        ssum += __shfl_xor(ssum, 32);
        const float inv = __builtin_amdgcn_rcpf(ssum);

        half4v bfrag;   // B[k=j=quad*4+jj][n=i=m] = attn[i][j]
        #pragma unroll
        for (int jj = 0; jj < 4; ++jj) bfrag[jj] = (_Float16)(p_[jj] * inv);

        #pragma unroll
        for (int p = 0; p < 2; ++p) {
            float4v ct = hpt[2 * hh + p];       // A[m=d'][k=j=quad*4+t]
            half4v afrag;
            #pragma unroll
            for (int t = 0; t < 4; ++t) afrag[t] = (_Float16)ct[t];
            float4v z = (float4v){0.f, 0.f, 0.f, 0.f};
            z = __builtin_amdgcn_mfma_f32_16x16x16f16(afrag, bfrag, z, 0, 0, 0);
            ushort4v o;
            #pragma unroll
            for (int t = 0; t < 4; ++t) {
                float x = z[t];
                float ex = __expf(x) - 1.f;    // elu
                x = (x > 0.f) ? x : ex;
                o[t] = f2bf(x);
            }
            *(ushort4v*)&g_bf[((size_t)b * 4 + h) * 512 + m * 32 + p * 16 + quad * 4] = o;
        }
    }

    // ---- small GEMVs vs WsT: half 0 -> b1,wf; half 1 -> V1->v + out seed ----
    const int e = lane & 31, khalf = lane >> 5;
    const float* srow = states + (size_t)b * 128 + khalf * 64;
    if (half == 0) {
        #pragma unroll
        for (int set = 0; set < 2; ++set) {
            const float* wrow = WsT + (size_t)(set * 32 + e) * 128 + khalf * 64;
            float a = 0.f;
            #pragma unroll
            for (int kk = 0; kk < 16; ++kk) {
                float4 wv = *(const float4*)(wrow + kk * 4);
                float4 sv = *(const float4*)(srow + kk * 4);
                a += wv.x * sv.x + wv.y * sv.y + wv.z * sv.z + wv.w * sv.w;
            }
            a += __shfl_xor(a, 32);
            if (khalf == 0) {
                if (set == 0) b1v[b * 32 + e] = a + b1_b[e];
                else          wfv[b * 32 + e] = fabsf(a + wf_b[e]);
            }
        }
    } else {
        const float* wrow = WsT + (size_t)(64 + e) * 128 + khalf * 64;
        float a = 0.f;
        #pragma unroll
        for (int kk = 0; kk < 16; ++kk) {
            float4 wv = *(const float4*)(wrow + kk * 4);
            float4 sv = *(const float4*)(srow + kk * 4);
            a += wv.x * sv.x + wv.y * sv.y + wv.z * sv.z + wv.w * sv.w;
        }
        a += __shfl_xor(a, 32);
        float r3 = fmaxf(a + V1_b[e], 0.f) * V2_W[e];
        r3 += __shfl_xor(r3, 1);  r3 += __shfl_xor(r3, 2);
        r3 += __shfl_xor(r3, 4);  r3 += __shfl_xor(r3, 8);
        r3 += __shfl_xor(r3, 16);
        if (lane == 0) out[b] = r3 + V2_b[0];
    }
}

// ---------------------------------------------------------------------------
// K2_mix: fused GEMM + contraction + FULL epilogue (absorbs k3).
// Block = (32-row strip, e-group of 8 e's); grid 128x4 x 4 waves. Loop h:
//   Phase 1: GEMM 32 rows x 256 cols (A from states fp32 in-register,
//            B=w1sT from L2), fixup -> fp32 LDS tile; barrier.
//   Phase 2: 8 rows/wave, 1 contraction MFMA vs g; Sacc[rr] += |z|
//            (h-mean and n-sum deferred — abs commutes); barrier.
// Epilogue: qs, n-shuffle-reduce, b1+elu+wf, e-sum, atomicAdd -> out.
// ---------------------------------------------------------------------------
__global__ __launch_bounds__(256) void k2_mix(
    const float* __restrict__ states,           // [4096][128] fp32
    const unsigned short* __restrict__ w1sT,    // [4096 cols][128 k]
    const unsigned short* __restrict__ g_bf,    // [4096][4][16][32]
    const float* __restrict__ agent_qs,         // [4096][16]
    const float* __restrict__ uncertainty,      // [4096]
    const float* __restrict__ w1s_W,            // row 128 used
    const float* __restrict__ w1s_b,
    const float* __restrict__ b1v, const float* __restrict__ wfv,
    float* __restrict__ out)                    // pre-seeded with v
{
    const int r0 = blockIdx.x * 32;
    const int eg = blockIdx.y;
    const int wave = threadIdx.x >> 6;
    const int lane = threadIdx.x & 63, m = lane & 15, quad = lane >> 4;
    __shared__ __align__(16) float Wt[32 * 292];   // [row][e_loc*36 + d] 37KB

    // A-frags from states fp32 (rows r0..r0+31), register-resident
    short8 a[2][4];
    #pragma unroll
    for (int mt = 0; mt < 2; ++mt)
        #pragma unroll
        for (int ks = 0; ks < 4; ++ks) {
            const float* sp = states + (size_t)(r0 + mt * 16 + m) * 128 + ks * 32 + quad * 8;
            float4 f0 = *(const float4*)sp;
            float4 f1 = *(const float4*)(sp + 4);
            a[mt][ks] = pack8(f0, f1);
        }
    float us[2][4];
    #pragma unroll
    for (int mt = 0; mt < 2; ++mt)
        #pragma unroll
        for (int reg = 0; reg < 4; ++reg)
            us[mt][reg] = uncertainty[r0 + mt * 16 + quad * 4 + reg];
    float qs_r[8];
    #pragma unroll
    for (int rr = 0; rr < 8; ++rr)
        qs_r[rr] = agent_qs[(r0 + wave * 8 + rr) * 16 + m];

    const float* w128 = w1s_W + (size_t)128 * 4096;
    float Sacc[8][4] = {};

    for (int h = 0; h < 4; ++h) {
        const int cbase = h * 1024 + eg * 256;

        // ---- Phase 1: wave w -> col-tiles w*4..+4 (e_loc 2w, 2w+1) ----
        #pragma unroll
        for (int t = 0; t < 4; ++t) {
            const int c_loc = (wave * 4 + t) * 16 + m;
            const int cg = cbase + c_loc;
            const float wfix = w128[cg], bias = w1s_b[cg];
            float4v acc0 = (float4v){0.f, 0.f, 0.f, 0.f};
            float4v acc1 = (float4v){0.f, 0.f, 0.f, 0.f};
            #pragma unroll
            for (int ks = 0; ks < 4; ++ks) {
                short8 bfr = *(const short8*)&w1sT[(size_t)cg * 128 + ks * 32 + quad * 8];
                acc0 = __builtin_amdgcn_mfma_f32_16x16x32_bf16(a[0][ks], bfr, acc0, 0, 0, 0);
                acc1 = __builtin_amdgcn_mfma_f32_16x16x32_bf16(a[1][ks], bfr, acc1, 0, 0, 0);
            }
            const int el = c_loc >> 5, d = c_loc & 31;
            #pragma unroll
            for (int reg = 0; reg < 4; ++reg) {
                Wt[(quad * 4 + reg) * 292 + el * 36 + d]      = acc0[reg] + us[0][reg] * wfix + bias;
                Wt[(16 + quad * 4 + reg) * 292 + el * 36 + d] = acc1[reg] + us[1][reg] * wfix + bias;
            }
        }
        __syncthreads();

        // ---- Phase 2: wave w -> rows w*8..+8; Sacc += |z| ----
        #pragma unroll
        for (int rr = 0; rr < 8; ++rr) {
            const int r = wave * 8 + rr;
            const float* wrow = &Wt[r * 292 + (m & 7) * 36 + quad * 8];
            float4 w0 = *(const float4*)wrow;
            float4 w1 = *(const float4*)(wrow + 4);
            short8 af = pack8(w0, w1);               // A[e' = m&7][d]
            short8 gf = *(const short8*)&g_bf[((size_t)(r0 + r) * 4 + h) * 512 + m * 32 + quad * 8];
            float4v z = (float4v){0.f, 0.f, 0.f, 0.f};
            z = __builtin_amdgcn_mfma_f32_16x16x32_bf16(af, gf, z, 0, 0, 0);
            #pragma unroll
            for (int reg = 0; reg < 4; ++reg)
                Sacc[rr][reg] += fabsf(z[reg]);
        }
        __syncthreads();
    }

    // ---- Epilogue: qs, n-reduce, b1+elu+wf, e-sum, atomic into out ----
    #pragma unroll
    for (int rr = 0; rr < 8; ++rr) {
        const int r = r0 + wave * 8 + rr;
        float sn[4];
        #pragma unroll
        for (int reg = 0; reg < 4; ++reg) sn[reg] = Sacc[rr][reg] * qs_r[rr];
        #pragma unroll
        for (int mask = 1; mask <= 8; mask <<= 1) {
            #pragma unroll
            for (int reg = 0; reg < 4; ++reg) sn[reg] += __shfl_xor(sn[reg], mask);
        }
        // e = (quad*4+reg)&7; quads 0/1 cover e 0..7, quads 2/3 duplicate
        const float* bb = &b1v[(size_t)r * 32 + eg * 8 + (quad & 1) * 4];
        const float* ww = &wfv[(size_t)r * 32 + eg * 8 + (quad & 1) * 4];
        float4 b4 = *(const float4*)bb;
        float4 w4 = *(const float4*)ww;
        float bq[4] = {b4.x, b4.y, b4.z, b4.w};
        float wq[4] = {w4.x, w4.y, w4.z, w4.w};
        float local = 0.f;
        #pragma unroll
        for (int reg = 0; reg < 4; ++reg) {
            float hid = 0.25f * sn[reg] + bq[reg];
            hid = (hid > 0.f) ? hid : expm1f(hid);
            local = fmaf(hid, wq[reg], local);
        }
        local += __shfl_xor(local, 16);   // quad0+quad1 (2/3 duplicate)
        if (lane == 0) atomicAdd(&out[r], local);
    }
}

// ---------------------------------------------------------------------------
extern "C" void kernel_launch(void* const* d_in, const int* in_sizes, int n_in,
                              void* d_out, int out_size, void* d_ws, size_t ws_size,
                              hipStream_t stream)
{
    const float* agent_qs      = (const float*)d_in[0];
    const float* states        = (const float*)d_in[1];
    const float* hidden_states = (const float*)d_in[2];
    const float* uncertainty   = (const float*)d_in[3];
    const float* W_gat         = (const float*)d_in[4];
    const float* att_a         = (const float*)d_in[5];
    const float* w1s_W         = (const float*)d_in[6];
    const float* w1s_b         = (const float*)d_in[7];
    const float* b1_W          = (const float*)d_in[8];
    const float* b1_b          = (const float*)d_in[9];
    const float* wf_W          = (const float*)d_in[10];
    const float* wf_b          = (const float*)d_in[11];
    const float* V1_W          = (const float*)d_in[12];
    const float* V1_b          = (const float*)d_in[13];
    const float* V2_W          = (const float*)d_in[14];
    const float* V2_b          = (const float*)d_in[15];

    char* w = (char*)d_ws;
    unsigned short* w1sT    = (unsigned short*)w;  w += (size_t)524288 * 2;
    unsigned short* WgT     = (unsigned short*)w;  w += (size_t)144 * 64 * 2;
    float* WsT              = (float*)w;           w += (size_t)12288 * 4;
    unsigned short* g_bf    = (unsigned short*)w;  w += (size_t)8388608 * 2;
    float* b1v              = (float*)w;           w += (size_t)131072 * 4;
    float* wfv              = (float*)w;           w += (size_t)131072 * 4;
    float* out              = (float*)d_out;

    k0_prep<<<258, 256, 0, stream>>>(w1s_W, W_gat, att_a, b1_W, wf_W, V1_W,
                                     w1sT, WgT, WsT);

    k1_gat<<<2048, 256, 0, stream>>>(hidden_states, WgT, states, WsT,
        b1_b, wf_b, V1_b, V2_W, V2_b, g_bf, b1v, wfv, out);

    dim3 gmix(128, 4);
    k2_mix<<<gmix, 256, 0, stream>>>(states, w1sT, g_bf, agent_qs, uncertainty,
                                     w1s_W, w1s_b, b1v, wfv, out);
}

// Round 9
// 150.014 us; speedup vs baseline: 1.2110x; 1.2110x over previous
//
#include <hip/hip_runtime.h>
#include <math.h>

// N_AGENTS=16, RNN_H=64, N_HEADS=4, GAT_D=32, EMB=32, SDIM=128, B=4096 rows

typedef __attribute__((ext_vector_type(8))) short short8;
typedef __attribute__((ext_vector_type(8))) unsigned short ushort8;
typedef __attribute__((ext_vector_type(4))) unsigned short ushort4v;
typedef __attribute__((ext_vector_type(4))) float float4v;
typedef __attribute__((ext_vector_type(4))) _Float16 half4v;

static __device__ inline unsigned short f2bf(float f) {
    unsigned int x;
    __builtin_memcpy(&x, &f, 4);
    unsigned int r = x + 0x7fffu + ((x >> 16) & 1u);   // RNE
    return (unsigned short)(r >> 16);
}

static __device__ inline short8 pack8(float4 f0, float4 f1) {
    ushort8 o;
    o[0] = f2bf(f0.x); o[1] = f2bf(f0.y); o[2] = f2bf(f0.z); o[3] = f2bf(f0.w);
    o[4] = f2bf(f1.x); o[5] = f2bf(f1.y); o[6] = f2bf(f1.z); o[7] = f2bf(f1.w);
    short8 s;
    __builtin_memcpy(&s, &o, 16);
    return s;
}

// ---------------------------------------------------------------------------
// K0: prep + batched small GEMVs.
//  blocks 0..255   : w1s_W -> w1sTf, FRAG-MAJOR bf16: for col-tile ct,
//                    element (col=ct*16+m, k=ks*32+q*8+j) at
//                    w1sTf[ct*2048 + ks*512 + (q*16+m)*8 + j]  (1KB/frag-load)
//  block 256       : W_gat -> WgTf frag-major (9 tiles incl. fused src/dst
//                    attention projections as tile 8, cols m<8; m>=8 zero)
//  blocks 257..320 : MFMA GEMVs: [64 rows] x (b1|wf|V1) -> b1v, wfv,
//                    out = v  (kills per-row 48KB strided re-reads)
// ---------------------------------------------------------------------------
__global__ __launch_bounds__(256) void k0_prep(
    const float* __restrict__ w1s_W,     // [129][4096]
    const float* __restrict__ W_gat,     // [64][128]
    const float* __restrict__ att_a,     // [4][64]
    const float* __restrict__ states,    // [4096][128]
    const float* __restrict__ b1_W, const float* __restrict__ b1_b,
    const float* __restrict__ wf_W, const float* __restrict__ wf_b,
    const float* __restrict__ V1_W, const float* __restrict__ V1_b,
    const float* __restrict__ V2_W, const float* __restrict__ V2_b,
    unsigned short* __restrict__ w1sTf,  // [256 tiles][2048] bf16 frag-major
    unsigned short* __restrict__ WgTf,   // [9 tiles][1024] bf16 frag-major
    float* __restrict__ b1v, float* __restrict__ wfv,
    float* __restrict__ out)             // seeded with v
{
    __shared__ __align__(16) char SMEM[49152];
    const int tid = threadIdx.x, bx = blockIdx.x;

    if (bx < 256) {
        unsigned short* T = (unsigned short*)SMEM;    // [16 cols][136]
        const int c0 = bx * 16;
        const int cc = tid & 15, kr = tid >> 4;
        #pragma unroll
        for (int t = 0; t < 8; ++t) {
            int k = t * 16 + kr;
            T[cc * 136 + k] = f2bf(w1s_W[(size_t)k * 4096 + c0 + cc]);
        }
        __syncthreads();
        const int ks = tid >> 6, q = (tid >> 4) & 3, mm = tid & 15;
        *(ushort8*)&w1sTf[(size_t)bx * 2048 + tid * 8] =
            *(const ushort8*)&T[mm * 136 + ks * 32 + q * 8];
    } else if (bx == 256) {
        unsigned short* T = (unsigned short*)SMEM;    // [128 cols][72]
        #pragma unroll
        for (int t = 0; t < 32; ++t) {
            int i = t * 256 + tid;
            int k = i >> 7, c = i & 127;
            T[c * 72 + k] = f2bf(W_gat[k * 128 + c]);
        }
        __syncthreads();
        // tiles 0..7 frag-major
        #pragma unroll
        for (int t = 0; t < 4; ++t) {
            int i = t * 256 + tid;            // < 1024 ushort8 groups
            int nt = i >> 7, w = i & 127;
            int kh = w >> 6, q = (w >> 4) & 3, mm = w & 15;
            *(ushort8*)&WgTf[nt * 1024 + w * 8] =
                *(const ushort8*)&T[(nt * 16 + mm) * 72 + kh * 32 + q * 8];
        }
        // tile 8: fused attention projections (m = h: src, m = 4+h: dst)
        {
            const int k = tid >> 2, h = tid & 3;
            float ss = 0.f, dd = 0.f;
            #pragma unroll
            for (int d = 0; d < 32; ++d) {
                float wv = W_gat[k * 128 + h * 32 + d];
                ss = fmaf(wv, att_a[h * 64 + d], ss);
                dd = fmaf(wv, att_a[h * 64 + 32 + d], dd);
            }
            const int base = 8192 + (k >> 5) * 512 + ((k >> 3) & 3) * 128 + (k & 7);
            WgTf[base + h * 8]       = f2bf(ss);
            WgTf[base + (4 + h) * 8] = f2bf(dd);
        }
        #pragma unroll
        for (int t = 0; t < 2; ++t) {         // zero cols m = 8..15
            int i = t * 256 + tid;            // < 512
            int kh = i >> 8, q = (i >> 6) & 3, mm = 8 + ((i >> 3) & 7), j = i & 7;
            WgTf[8192 + kh * 512 + q * 128 + mm * 8 + j] = 0;
        }
    } else {
        // ---- MFMA GEMV block: 64 rows, 4 waves x 16 rows ----
        float* WL = (float*)SMEM;             // [3][128][32] = 48KB
        for (int i = tid; i < 12288; i += 256)
            WL[i] = (i < 4096) ? b1_W[i] : (i < 8192 ? wf_W[i - 4096] : V1_W[i - 8192]);
        __syncthreads();

        const int wave = tid >> 6, lane = tid & 63, mm = lane & 15, q = lane >> 4;
        const int b0w = (bx - 257) * 64 + wave * 16;

        short8 a[4];
        #pragma unroll
        for (int ks = 0; ks < 4; ++ks) {
            const float* sp = states + (size_t)(b0w + mm) * 128 + ks * 32 + q * 8;
            a[ks] = pack8(*(const float4*)sp, *(const float4*)(sp + 4));
        }
        float4v accT[6];
        #pragma unroll
        for (int nt = 0; nt < 6; ++nt) accT[nt] = (float4v){0.f, 0.f, 0.f, 0.f};
        #pragma unroll
        for (int nt = 0; nt < 6; ++nt) {
            const int set = nt >> 1, e = (nt & 1) * 16 + mm;
            #pragma unroll
            for (int ks = 0; ks < 4; ++ks) {
                ushort8 bfu;
                #pragma unroll
                for (int j = 0; j < 8; ++j)
                    bfu[j] = f2bf(WL[set * 4096 + (ks * 32 + q * 8 + j) * 32 + e]);
                short8 bf;
                __builtin_memcpy(&bf, &bfu, 16);
                accT[nt] = __builtin_amdgcn_mfma_f32_16x16x32_bf16(a[ks], bf, accT[nt], 0, 0, 0);
            }
        }
        float vsum[4] = {0.f, 0.f, 0.f, 0.f};
        #pragma unroll
        for (int p = 0; p < 2; ++p) {
            const int e = p * 16 + mm;
            const float bb1 = b1_b[e], bwf = wf_b[e], bv1 = V1_b[e], v2 = V2_W[e];
            #pragma unroll
            for (int reg = 0; reg < 4; ++reg) {
                const int row = b0w + q * 4 + reg;
                b1v[(size_t)row * 32 + e] = accT[p][reg] + bb1;
                wfv[(size_t)row * 32 + e] = fabsf(accT[2 + p][reg] + bwf);
                vsum[reg] += fmaxf(accT[4 + p][reg] + bv1, 0.f) * v2;
            }
        }
        #pragma unroll
        for (int reg = 0; reg < 4; ++reg) {
            vsum[reg] += __shfl_xor(vsum[reg], 1);
            vsum[reg] += __shfl_xor(vsum[reg], 2);
            vsum[reg] += __shfl_xor(vsum[reg], 4);
            vsum[reg] += __shfl_xor(vsum[reg], 8);
        }
        if (mm == 0) {
            #pragma unroll
            for (int reg = 0; reg < 4; ++reg)
                out[b0w + q * 4 + reg] = vsum[reg] + V2_b[0];
        }
    }
}

// ---------------------------------------------------------------------------
// K1: GAT, 1 wave = 1 batch row, no GEMVs. 18 coalesced WgTf frag loads +
// 18 MFMA (hp + proj), LDS scratch for src/dst routing, softmax, f16 MFMA2,
// dense g stores.
// ---------------------------------------------------------------------------
__global__ __launch_bounds__(256) void k1_gat(
    const float* __restrict__ hidden_states,  // [4096*16][64] fp32
    const unsigned short* __restrict__ WgTf,  // [9][1024] bf16 frag-major
    unsigned short* __restrict__ g_bf)        // [B][4][16][32] bf16
{
    const int wave = threadIdx.x >> 6;
    const int b = blockIdx.x * 4 + wave;
    const int lane = threadIdx.x & 63, m = lane & 15, quad = lane >> 4;
    __shared__ __align__(16) float sc[4 * 320];   // per-wave scratch, 5KB
    float* scr = &sc[wave * 320];

    // ---- MFMA1: 8 hp tiles + proj tile ----
    const float* hrow = hidden_states + ((size_t)b * 16 + m) * 64;
    float4 f0 = *(const float4*)(hrow + quad * 8);
    float4 f1 = *(const float4*)(hrow + quad * 8 + 4);
    short8 a0 = pack8(f0, f1);
    f0 = *(const float4*)(hrow + 32 + quad * 8);
    f1 = *(const float4*)(hrow + 32 + quad * 8 + 4);
    short8 a1 = pack8(f0, f1);

    float4v hpt[9];
    #pragma unroll
    for (int nt = 0; nt < 9; ++nt) {
        short8 bf0 = *(const short8*)&WgTf[nt * 1024 + lane * 8];
        short8 bf1 = *(const short8*)&WgTf[nt * 1024 + 512 + lane * 8];
        float4v z = (float4v){0.f, 0.f, 0.f, 0.f};
        z = __builtin_amdgcn_mfma_f32_16x16x32_bf16(a0, bf0, z, 0, 0, 0);
        z = __builtin_amdgcn_mfma_f32_16x16x32_bf16(a1, bf1, z, 0, 0, 0);
        hpt[nt] = z;
    }

    // stash proj tile transposed: scr[col*20 + row]
    {
        float4 pr = {hpt[8][0], hpt[8][1], hpt[8][2], hpt[8][3]};
        *(float4*)&scr[m * 20 + quad * 4] = pr;
    }

    // ---- per head: softmax + MFMA2 ----
    #pragma unroll
    for (int h = 0; h < 4; ++h) {
        const float src_m = scr[h * 20 + m];                        // src[i=m]
        float4 pdv = *(const float4*)&scr[(4 + h) * 20 + quad * 4]; // dst[j]
        float pd[4] = {pdv.x, pdv.y, pdv.z, pdv.w};

        float e_[4];
        #pragma unroll
        for (int jj = 0; jj < 4; ++jj) {
            float x = src_m + pd[jj];
            e_[jj] = fmaxf(x, 0.2f * x);       // leaky_relu(0.2)
        }
        float mx = fmaxf(fmaxf(e_[0], e_[1]), fmaxf(e_[2], e_[3]));
        mx = fmaxf(mx, __shfl_xor(mx, 16));
        mx = fmaxf(mx, __shfl_xor(mx, 32));
        float p_[4], ssum = 0.f;
        #pragma unroll
        for (int jj = 0; jj < 4; ++jj) { p_[jj] = __expf(e_[jj] - mx); ssum += p_[jj]; }
        ssum += __shfl_xor(ssum, 16);
        ssum += __shfl_xor(ssum, 32);
        const float inv = __builtin_amdgcn_rcpf(ssum);

        half4v bfrag;   // B[k=j=quad*4+jj][n=i=m] = attn[i][j]
        #pragma unroll
        for (int jj = 0; jj < 4; ++jj) bfrag[jj] = (_Float16)(p_[jj] * inv);

        #pragma unroll
        for (int p = 0; p < 2; ++p) {
            float4v ct = hpt[2 * h + p];       // A[m=d'][k=j=quad*4+t]
            half4v afrag;
            #pragma unroll
            for (int t = 0; t < 4; ++t) afrag[t] = (_Float16)ct[t];
            float4v z = (float4v){0.f, 0.f, 0.f, 0.f};
            z = __builtin_amdgcn_mfma_f32_16x16x16f16(afrag, bfrag, z, 0, 0, 0);
            ushort4v o;
            #pragma unroll
            for (int t = 0; t < 4; ++t) {
                float x = z[t];
                float ex = __expf(x) - 1.f;    // elu
                x = (x > 0.f) ? x : ex;
                o[t] = f2bf(x);
            }
            *(ushort4v*)&g_bf[((size_t)b * 4 + h) * 512 + m * 32 + p * 16 + quad * 4] = o;
        }
    }
}

// ---------------------------------------------------------------------------
// K2_mix: fused GEMM + contraction + epilogue. Block = (32-row strip,
// e-group); grid 128x4 x 4 waves; h looped inside. B-frags from FRAG-MAJOR
// w1sTf (coalesced 1KB loads). Deferred-abs h-accumulation; atomic out.
// ---------------------------------------------------------------------------
__global__ __launch_bounds__(256) void k2_mix(
    const float* __restrict__ states,           // [4096][128] fp32
    const unsigned short* __restrict__ w1sTf,   // [256 tiles][2048] frag-major
    const unsigned short* __restrict__ g_bf,    // [4096][4][16][32]
    const float* __restrict__ agent_qs,         // [4096][16]
    const float* __restrict__ uncertainty,      // [4096]
    const float* __restrict__ w1s_W,            // row 128 used
    const float* __restrict__ w1s_b,
    const float* __restrict__ b1v, const float* __restrict__ wfv,
    float* __restrict__ out)                    // pre-seeded with v
{
    const int r0 = blockIdx.x * 32;
    const int eg = blockIdx.y;
    const int wave = threadIdx.x >> 6;
    const int lane = threadIdx.x & 63, m = lane & 15, quad = lane >> 4;
    __shared__ __align__(16) float Wt[32 * 292];   // [row][e_loc*36 + d] 37KB

    // A-frags from states fp32 (rows r0..r0+31), register-resident
    short8 a[2][4];
    #pragma unroll
    for (int mt = 0; mt < 2; ++mt)
        #pragma unroll
        for (int ks = 0; ks < 4; ++ks) {
            const float* sp = states + (size_t)(r0 + mt * 16 + m) * 128 + ks * 32 + quad * 8;
            a[mt][ks] = pack8(*(const float4*)sp, *(const float4*)(sp + 4));
        }
    float us[2][4];
    #pragma unroll
    for (int mt = 0; mt < 2; ++mt)
        #pragma unroll
        for (int reg = 0; reg < 4; ++reg)
            us[mt][reg] = uncertainty[r0 + mt * 16 + quad * 4 + reg];
    float qs_r[8];
    #pragma unroll
    for (int rr = 0; rr < 8; ++rr)
        qs_r[rr] = agent_qs[(r0 + wave * 8 + rr) * 16 + m];

    const float* w128 = w1s_W + (size_t)128 * 4096;
    float Sacc[8][4] = {};

    for (int h = 0; h < 4; ++h) {
        // ---- Phase 1: wave w -> col-tiles w*4..+4 ----
        #pragma unroll
        for (int t = 0; t < 4; ++t) {
            const int ctl = wave * 4 + t;                // local col-tile
            const int ct = h * 64 + eg * 16 + ctl;       // global col-tile
            const int c_loc = ctl * 16 + m;
            const int cg = ct * 16 + m;
            const float wfix = w128[cg], bias = w1s_b[cg];
            float4v acc0 = (float4v){0.f, 0.f, 0.f, 0.f};
            float4v acc1 = (float4v){0.f, 0.f, 0.f, 0.f};
            #pragma unroll
            for (int ks = 0; ks < 4; ++ks) {
                short8 bfr = *(const short8*)&w1sTf[(size_t)ct * 2048 + ks * 512 + lane * 8];
                acc0 = __builtin_amdgcn_mfma_f32_16x16x32_bf16(a[0][ks], bfr, acc0, 0, 0, 0);
                acc1 = __builtin_amdgcn_mfma_f32_16x16x32_bf16(a[1][ks], bfr, acc1, 0, 0, 0);
            }
            const int el = c_loc >> 5, d = c_loc & 31;
            #pragma unroll
            for (int reg = 0; reg < 4; ++reg) {
                Wt[(quad * 4 + reg) * 292 + el * 36 + d]      = acc0[reg] + us[0][reg] * wfix + bias;
                Wt[(16 + quad * 4 + reg) * 292 + el * 36 + d] = acc1[reg] + us[1][reg] * wfix + bias;
            }
        }
        __syncthreads();

        // ---- Phase 2: wave w -> rows w*8..+8; Sacc += |z| ----
        #pragma unroll
        for (int rr = 0; rr < 8; ++rr) {
            const int r = wave * 8 + rr;
            const float* wrow = &Wt[r * 292 + (m & 7) * 36 + quad * 8];
            short8 af = pack8(*(const float4*)wrow, *(const float4*)(wrow + 4));
            short8 gf = *(const short8*)&g_bf[((size_t)(r0 + r) * 4 + h) * 512 + m * 32 + quad * 8];
            float4v z = (float4v){0.f, 0.f, 0.f, 0.f};
            z = __builtin_amdgcn_mfma_f32_16x16x32_bf16(af, gf, z, 0, 0, 0);
            #pragma unroll
            for (int reg = 0; reg < 4; ++reg)
                Sacc[rr][reg] += fabsf(z[reg]);
        }
        __syncthreads();
    }

    // ---- Epilogue: qs, n-reduce, b1+elu+wf, e-sum, atomic into out ----
    #pragma unroll
    for (int rr = 0; rr < 8; ++rr) {
        const int r = r0 + wave * 8 + rr;
        float sn[4];
        #pragma unroll
        for (int reg = 0; reg < 4; ++reg) sn[reg] = Sacc[rr][reg] * qs_r[rr];
        #pragma unroll
        for (int mask = 1; mask <= 8; mask <<= 1) {
            #pragma unroll
            for (int reg = 0; reg < 4; ++reg) sn[reg] += __shfl_xor(sn[reg], mask);
        }
        const float* bb = &b1v[(size_t)r * 32 + eg * 8 + (quad & 1) * 4];
        const float* ww = &wfv[(size_t)r * 32 + eg * 8 + (quad & 1) * 4];
        float4 b4 = *(const float4*)bb;
        float4 w4 = *(const float4*)ww;
        float bq[4] = {b4.x, b4.y, b4.z, b4.w};
        float wq[4] = {w4.x, w4.y, w4.z, w4.w};
        float local = 0.f;
        #pragma unroll
        for (int reg = 0; reg < 4; ++reg) {
            float hid = 0.25f * sn[reg] + bq[reg];
            hid = (hid > 0.f) ? hid : expm1f(hid);
            local = fmaf(hid, wq[reg], local);
        }
        local += __shfl_xor(local, 16);   // quad0+quad1 (2/3 duplicate)
        if (lane == 0) atomicAdd(&out[r], local);
    }
}

// ---------------------------------------------------------------------------
extern "C" void kernel_launch(void* const* d_in, const int* in_sizes, int n_in,
                              void* d_out, int out_size, void* d_ws, size_t ws_size,
                              hipStream_t stream)
{
    const float* agent_qs      = (const float*)d_in[0];
    const float* states        = (const float*)d_in[1];
    const float* hidden_states = (const float*)d_in[2];
    const float* uncertainty   = (const float*)d_in[3];
    const float* W_gat         = (const float*)d_in[4];
    const float* att_a         = (const float*)d_in[5];
    const float* w1s_W         = (const float*)d_in[6];
    const float* w1s_b         = (const float*)d_in[7];
    const float* b1_W          = (const float*)d_in[8];
    const float* b1_b          = (const float*)d_in[9];
    const float* wf_W          = (const float*)d_in[10];
    const float* wf_b          = (const float*)d_in[11];
    const float* V1_W          = (const float*)d_in[12];
    const float* V1_b          = (const float*)d_in[13];
    const float* V2_W          = (const float*)d_in[14];
    const float* V2_b          = (const float*)d_in[15];

    char* w = (char*)d_ws;
    unsigned short* w1sTf   = (unsigned short*)w;  w += (size_t)524288 * 2;
    unsigned short* WgTf    = (unsigned short*)w;  w += (size_t)9216 * 2;
    unsigned short* g_bf    = (unsigned short*)w;  w += (size_t)8388608 * 2;
    float* b1v              = (float*)w;           w += (size_t)131072 * 4;
    float* wfv              = (float*)w;           w += (size_t)131072 * 4;
    float* out              = (float*)d_out;

    k0_prep<<<321, 256, 0, stream>>>(w1s_W, W_gat, att_a, states,
                                     b1_W, b1_b, wf_W, wf_b, V1_W, V1_b,
                                     V2_W, V2_b, w1sTf, WgTf, b1v, wfv, out);

    k1_gat<<<1024, 256, 0, stream>>>(hidden_states, WgTf, g_bf);

    dim3 gmix(128, 4);
    k2_mix<<<gmix, 256, 0, stream>>>(states, w1sTf, g_bf, agent_qs, uncertainty,
                                     w1s_W, w1s_b, b1v, wfv, out);
}

// Round 10
// 136.002 us; speedup vs baseline: 1.3357x; 1.1030x over previous
//
#include <hip/hip_runtime.h>
#include <math.h>

// N_AGENTS=16, RNN_H=64, N_HEADS=4, GAT_D=32, EMB=32, SDIM=128, B=4096 rows

typedef __attribute__((ext_vector_type(8))) short short8;
typedef __attribute__((ext_vector_type(8))) unsigned short ushort8;
typedef __attribute__((ext_vector_type(4))) unsigned short ushort4v;
typedef __attribute__((ext_vector_type(4))) float float4v;
typedef __attribute__((ext_vector_type(4))) _Float16 half4v;

static __device__ inline unsigned short f2bf(float f) {
    unsigned int x;
    __builtin_memcpy(&x, &f, 4);
    unsigned int r = x + 0x7fffu + ((x >> 16) & 1u);   // RNE
    return (unsigned short)(r >> 16);
}

static __device__ inline short8 pack8(float4 f0, float4 f1) {
    ushort8 o;
    o[0] = f2bf(f0.x); o[1] = f2bf(f0.y); o[2] = f2bf(f0.z); o[3] = f2bf(f0.w);
    o[4] = f2bf(f1.x); o[5] = f2bf(f1.y); o[6] = f2bf(f1.z); o[7] = f2bf(f1.w);
    short8 s;
    __builtin_memcpy(&s, &o, 16);
    return s;
}

// ---------------------------------------------------------------------------
// K0: prep + batched small GEMVs.
//  blocks 0..255   : w1s_W -> w1sTf, FRAG-MAJOR bf16 (1KB coalesced frag loads)
//  block 256       : W_gat -> WgTf frag-major (9 tiles incl. fused attention
//                    projections as tile 8)
//  blocks 257..320 : MFMA GEMVs -> b1v, wfv, out = v
// ---------------------------------------------------------------------------
__global__ __launch_bounds__(256) void k0_prep(
    const float* __restrict__ w1s_W,     // [129][4096]
    const float* __restrict__ W_gat,     // [64][128]
    const float* __restrict__ att_a,     // [4][64]
    const float* __restrict__ states,    // [4096][128]
    const float* __restrict__ b1_W, const float* __restrict__ b1_b,
    const float* __restrict__ wf_W, const float* __restrict__ wf_b,
    const float* __restrict__ V1_W, const float* __restrict__ V1_b,
    const float* __restrict__ V2_W, const float* __restrict__ V2_b,
    unsigned short* __restrict__ w1sTf,  // [256 tiles][2048] bf16 frag-major
    unsigned short* __restrict__ WgTf,   // [9 tiles][1024] bf16 frag-major
    float* __restrict__ b1v, float* __restrict__ wfv,
    float* __restrict__ out)             // seeded with v
{
    __shared__ __align__(16) char SMEM[49152];
    const int tid = threadIdx.x, bx = blockIdx.x;

    if (bx < 256) {
        unsigned short* T = (unsigned short*)SMEM;    // [16 cols][136]
        const int c0 = bx * 16;
        const int cc = tid & 15, kr = tid >> 4;
        #pragma unroll
        for (int t = 0; t < 8; ++t) {
            int k = t * 16 + kr;
            T[cc * 136 + k] = f2bf(w1s_W[(size_t)k * 4096 + c0 + cc]);
        }
        __syncthreads();
        const int ks = tid >> 6, q = (tid >> 4) & 3, mm = tid & 15;
        *(ushort8*)&w1sTf[(size_t)bx * 2048 + tid * 8] =
            *(const ushort8*)&T[mm * 136 + ks * 32 + q * 8];
    } else if (bx == 256) {
        unsigned short* T = (unsigned short*)SMEM;    // [128 cols][72]
        #pragma unroll
        for (int t = 0; t < 32; ++t) {
            int i = t * 256 + tid;
            int k = i >> 7, c = i & 127;
            T[c * 72 + k] = f2bf(W_gat[k * 128 + c]);
        }
        __syncthreads();
        #pragma unroll
        for (int t = 0; t < 4; ++t) {
            int i = t * 256 + tid;            // < 1024 ushort8 groups
            int nt = i >> 7, w = i & 127;
            int kh = w >> 6, q = (w >> 4) & 3, mm = w & 15;
            *(ushort8*)&WgTf[nt * 1024 + w * 8] =
                *(const ushort8*)&T[(nt * 16 + mm) * 72 + kh * 32 + q * 8];
        }
        // tile 8: fused attention projections (m = h: src, m = 4+h: dst)
        {
            const int k = tid >> 2, h = tid & 3;
            float ss = 0.f, dd = 0.f;
            #pragma unroll
            for (int d = 0; d < 32; ++d) {
                float wv = W_gat[k * 128 + h * 32 + d];
                ss = fmaf(wv, att_a[h * 64 + d], ss);
                dd = fmaf(wv, att_a[h * 64 + 32 + d], dd);
            }
            const int base = 8192 + (k >> 5) * 512 + ((k >> 3) & 3) * 128 + (k & 7);
            WgTf[base + h * 8]       = f2bf(ss);
            WgTf[base + (4 + h) * 8] = f2bf(dd);
        }
        #pragma unroll
        for (int t = 0; t < 2; ++t) {         // zero cols m = 8..15
            int i = t * 256 + tid;            // < 512
            int kh = i >> 8, q = (i >> 6) & 3, mm = 8 + ((i >> 3) & 7), j = i & 7;
            WgTf[8192 + kh * 512 + q * 128 + mm * 8 + j] = 0;
        }
    } else {
        // ---- MFMA GEMV block: 64 rows, 4 waves x 16 rows ----
        float* WL = (float*)SMEM;             // [3][128][32] = 48KB
        for (int i = tid; i < 12288; i += 256)
            WL[i] = (i < 4096) ? b1_W[i] : (i < 8192 ? wf_W[i - 4096] : V1_W[i - 8192]);
        __syncthreads();

        const int wave = tid >> 6, lane = tid & 63, mm = lane & 15, q = lane >> 4;
        const int b0w = (bx - 257) * 64 + wave * 16;

        short8 a[4];
        #pragma unroll
        for (int ks = 0; ks < 4; ++ks) {
            const float* sp = states + (size_t)(b0w + mm) * 128 + ks * 32 + q * 8;
            a[ks] = pack8(*(const float4*)sp, *(const float4*)(sp + 4));
        }
        float4v accT[6];
        #pragma unroll
        for (int nt = 0; nt < 6; ++nt) accT[nt] = (float4v){0.f, 0.f, 0.f, 0.f};
        #pragma unroll
        for (int nt = 0; nt < 6; ++nt) {
            const int set = nt >> 1, e = (nt & 1) * 16 + mm;
            #pragma unroll
            for (int ks = 0; ks < 4; ++ks) {
                ushort8 bfu;
                #pragma unroll
                for (int j = 0; j < 8; ++j)
                    bfu[j] = f2bf(WL[set * 4096 + (ks * 32 + q * 8 + j) * 32 + e]);
                short8 bf;
                __builtin_memcpy(&bf, &bfu, 16);
                accT[nt] = __builtin_amdgcn_mfma_f32_16x16x32_bf16(a[ks], bf, accT[nt], 0, 0, 0);
            }
        }
        float vsum[4] = {0.f, 0.f, 0.f, 0.f};
        #pragma unroll
        for (int p = 0; p < 2; ++p) {
            const int e = p * 16 + mm;
            const float bb1 = b1_b[e], bwf = wf_b[e], bv1 = V1_b[e], v2 = V2_W[e];
            #pragma unroll
            for (int reg = 0; reg < 4; ++reg) {
                const int row = b0w + q * 4 + reg;
                b1v[(size_t)row * 32 + e] = accT[p][reg] + bb1;
                wfv[(size_t)row * 32 + e] = fabsf(accT[2 + p][reg] + bwf);
                vsum[reg] += fmaxf(accT[4 + p][reg] + bv1, 0.f) * v2;
            }
        }
        #pragma unroll
        for (int reg = 0; reg < 4; ++reg) {
            vsum[reg] += __shfl_xor(vsum[reg], 1);
            vsum[reg] += __shfl_xor(vsum[reg], 2);
            vsum[reg] += __shfl_xor(vsum[reg], 4);
            vsum[reg] += __shfl_xor(vsum[reg], 8);
        }
        if (mm == 0) {
            #pragma unroll
            for (int reg = 0; reg < 4; ++reg)
                out[b0w + q * 4 + reg] = vsum[reg] + V2_b[0];
        }
    }
}

// ---------------------------------------------------------------------------
// K1: GAT, 1 wave = 1 batch row. 18 coalesced WgTf frag loads + 18 MFMA
// (hp + proj), LDS scratch for src/dst routing, softmax, f16 MFMA2,
// dense g stores.
// ---------------------------------------------------------------------------
__global__ __launch_bounds__(256) void k1_gat(
    const float* __restrict__ hidden_states,  // [4096*16][64] fp32
    const unsigned short* __restrict__ WgTf,  // [9][1024] bf16 frag-major
    unsigned short* __restrict__ g_bf)        // [B][4][16][32] bf16
{
    const int wave = threadIdx.x >> 6;
    const int b = blockIdx.x * 4 + wave;
    const int lane = threadIdx.x & 63, m = lane & 15, quad = lane >> 4;
    __shared__ __align__(16) float sc[4 * 320];   // per-wave scratch, 5KB
    float* scr = &sc[wave * 320];

    // ---- MFMA1: 8 hp tiles + proj tile ----
    const float* hrow = hidden_states + ((size_t)b * 16 + m) * 64;
    float4 f0 = *(const float4*)(hrow + quad * 8);
    float4 f1 = *(const float4*)(hrow + quad * 8 + 4);
    short8 a0 = pack8(f0, f1);
    f0 = *(const float4*)(hrow + 32 + quad * 8);
    f1 = *(const float4*)(hrow + 32 + quad * 8 + 4);
    short8 a1 = pack8(f0, f1);

    float4v hpt[9];
    #pragma unroll
    for (int nt = 0; nt < 9; ++nt) {
        short8 bf0 = *(const short8*)&WgTf[nt * 1024 + lane * 8];
        short8 bf1 = *(const short8*)&WgTf[nt * 1024 + 512 + lane * 8];
        float4v z = (float4v){0.f, 0.f, 0.f, 0.f};
        z = __builtin_amdgcn_mfma_f32_16x16x32_bf16(a0, bf0, z, 0, 0, 0);
        z = __builtin_amdgcn_mfma_f32_16x16x32_bf16(a1, bf1, z, 0, 0, 0);
        hpt[nt] = z;
    }

    // stash proj tile transposed: scr[col*20 + row]
    {
        float4 pr = {hpt[8][0], hpt[8][1], hpt[8][2], hpt[8][3]};
        *(float4*)&scr[m * 20 + quad * 4] = pr;
    }

    // ---- per head: softmax + MFMA2 ----
    #pragma unroll
    for (int h = 0; h < 4; ++h) {
        const float src_m = scr[h * 20 + m];                        // src[i=m]
        float4 pdv = *(const float4*)&scr[(4 + h) * 20 + quad * 4]; // dst[j]
        float pd[4] = {pdv.x, pdv.y, pdv.z, pdv.w};

        float e_[4];
        #pragma unroll
        for (int jj = 0; jj < 4; ++jj) {
            float x = src_m + pd[jj];
            e_[jj] = fmaxf(x, 0.2f * x);       // leaky_relu(0.2)
        }
        float mx = fmaxf(fmaxf(e_[0], e_[1]), fmaxf(e_[2], e_[3]));
        mx = fmaxf(mx, __shfl_xor(mx, 16));
        mx = fmaxf(mx, __shfl_xor(mx, 32));
        float p_[4], ssum = 0.f;
        #pragma unroll
        for (int jj = 0; jj < 4; ++jj) { p_[jj] = __expf(e_[jj] - mx); ssum += p_[jj]; }
        ssum += __shfl_xor(ssum, 16);
        ssum += __shfl_xor(ssum, 32);
        const float inv = __builtin_amdgcn_rcpf(ssum);

        half4v bfrag;   // B[k=j=quad*4+jj][n=i=m] = attn[i][j]
        #pragma unroll
        for (int jj = 0; jj < 4; ++jj) bfrag[jj] = (_Float16)(p_[jj] * inv);

        #pragma unroll
        for (int p = 0; p < 2; ++p) {
            float4v ct = hpt[2 * h + p];       // A[m=d'][k=j=quad*4+t]
            half4v afrag;
            #pragma unroll
            for (int t = 0; t < 4; ++t) afrag[t] = (_Float16)ct[t];
            float4v z = (float4v){0.f, 0.f, 0.f, 0.f};
            z = __builtin_amdgcn_mfma_f32_16x16x16f16(afrag, bfrag, z, 0, 0, 0);
            ushort4v o;
            #pragma unroll
            for (int t = 0; t < 4; ++t) {
                float x = z[t];
                float ex = __expf(x) - 1.f;    // elu
                x = (x > 0.f) ? x : ex;
                o[t] = f2bf(x);
            }
            *(ushort4v*)&g_bf[((size_t)b * 4 + h) * 512 + m * 32 + p * 16 + quad * 4] = o;
        }
    }
}

// ---------------------------------------------------------------------------
// K2_mix v2: occupancy-first fused GEMM + contraction + epilogue.
// Block = (16-row strip, e-group of 8 e's); grid (256,4) = 1024 blocks x
// 4 waves (16 waves/CU). Per h: phase1 GEMM 16 rows x 256 cols (1 m-tile
// A-frags, frag-major B, 16 MFMA/wave) -> bf16 LDS (double-buffered, 21KB,
// e-stride 40 / row-stride 328: conflict-free b128 phase-2 reads); gf
// prefetch; ONE barrier; phase2: 4 rows/wave, direct-bf16 A-frag MFMA vs g,
// deferred-abs h-accumulation. Epilogue: qs, n-reduce, b1+elu+wf, atomic out.
// ---------------------------------------------------------------------------
__global__ __launch_bounds__(256) void k2_mix(
    const float* __restrict__ states,           // [4096][128] fp32
    const unsigned short* __restrict__ w1sTf,   // [256 tiles][2048] frag-major
    const unsigned short* __restrict__ g_bf,    // [4096][4][16][32]
    const float* __restrict__ agent_qs,         // [4096][16]
    const float* __restrict__ uncertainty,      // [4096]
    const float* __restrict__ w1s_W,            // row 128 used
    const float* __restrict__ w1s_b,
    const float* __restrict__ b1v, const float* __restrict__ wfv,
    float* __restrict__ out)                    // pre-seeded with v
{
    const int r0 = blockIdx.x * 16;
    const int eg = blockIdx.y;
    const int wave = threadIdx.x >> 6;
    const int lane = threadIdx.x & 63, m = lane & 15, quad = lane >> 4;
    // dbuf bf16 tile: [2][16 rows][8 e x 40 + pad], row stride 328 (16B-mult)
    __shared__ __align__(16) unsigned short Wt[2][16 * 328];   // 21KB

    // A-frags: one m-tile, rows r0..r0+15
    short8 a[4];
    #pragma unroll
    for (int ks = 0; ks < 4; ++ks) {
        const float* sp = states + (size_t)(r0 + m) * 128 + ks * 32 + quad * 8;
        a[ks] = pack8(*(const float4*)sp, *(const float4*)(sp + 4));
    }
    float us[4];
    #pragma unroll
    for (int reg = 0; reg < 4; ++reg)
        us[reg] = uncertainty[r0 + quad * 4 + reg];
    float qs_r[4];
    #pragma unroll
    for (int rr = 0; rr < 4; ++rr)
        qs_r[rr] = agent_qs[(r0 + wave * 4 + rr) * 16 + m];

    const float* w128 = w1s_W + (size_t)128 * 4096;
    float Sacc[4][4] = {};

    #pragma unroll
    for (int h = 0; h < 4; ++h) {
        unsigned short* buf = &Wt[h & 1][0];

        // ---- Phase 1: wave w -> col-tiles w*4..+4 (16 MFMA) ----
        #pragma unroll
        for (int t = 0; t < 4; ++t) {
            const int ctl = wave * 4 + t;                // local col-tile
            const int ct = h * 64 + eg * 16 + ctl;       // global col-tile
            const int c_loc = ctl * 16 + m;
            const int cg = h * 1024 + eg * 256 + c_loc;
            const float wfix = w128[cg], bias = w1s_b[cg];
            float4v acc = (float4v){0.f, 0.f, 0.f, 0.f};
            #pragma unroll
            for (int ks = 0; ks < 4; ++ks) {
                short8 bfr = *(const short8*)&w1sTf[(size_t)ct * 2048 + ks * 512 + lane * 8];
                acc = __builtin_amdgcn_mfma_f32_16x16x32_bf16(a[ks], bfr, acc, 0, 0, 0);
            }
            const int el = c_loc >> 5, d = c_loc & 31;
            #pragma unroll
            for (int reg = 0; reg < 4; ++reg)
                buf[(quad * 4 + reg) * 328 + el * 40 + d] =
                    f2bf(acc[reg] + us[reg] * wfix + bias);
        }

        // prefetch g frags (global, independent of LDS) before the barrier
        short8 gf[4];
        #pragma unroll
        for (int rr = 0; rr < 4; ++rr)
            gf[rr] = *(const short8*)&g_bf[((size_t)(r0 + wave * 4 + rr) * 4 + h) * 512 + m * 32 + quad * 8];

        __syncthreads();

        // ---- Phase 2: wave w -> rows w*4..+4; Sacc += |z| ----
        #pragma unroll
        for (int rr = 0; rr < 4; ++rr) {
            const int r = wave * 4 + rr;
            short8 af = *(const short8*)&buf[r * 328 + (m & 7) * 40 + quad * 8];
            float4v z = (float4v){0.f, 0.f, 0.f, 0.f};
            z = __builtin_amdgcn_mfma_f32_16x16x32_bf16(af, gf[rr], z, 0, 0, 0);
            #pragma unroll
            for (int reg = 0; reg < 4; ++reg)
                Sacc[rr][reg] += fabsf(z[reg]);
        }
        // no second barrier: next h writes the OTHER buffer; reuse of this
        // buffer (h+2) is separated by the h+1 barrier.
    }

    // ---- Epilogue: qs, n-reduce, b1+elu+wf, e-sum, atomic into out ----
    #pragma unroll
    for (int rr = 0; rr < 4; ++rr) {
        const int r = r0 + wave * 4 + rr;
        float sn[4];
        #pragma unroll
        for (int reg = 0; reg < 4; ++reg) sn[reg] = Sacc[rr][reg] * qs_r[rr];
        #pragma unroll
        for (int mask = 1; mask <= 8; mask <<= 1) {
            #pragma unroll
            for (int reg = 0; reg < 4; ++reg) sn[reg] += __shfl_xor(sn[reg], mask);
        }
        // e_local = quad*4+reg valid for quads 0/1 (2/3 duplicate)
        const float* bb = &b1v[(size_t)r * 32 + eg * 8 + (quad & 1) * 4];
        const float* ww = &wfv[(size_t)r * 32 + eg * 8 + (quad & 1) * 4];
        float4 b4 = *(const float4*)bb;
        float4 w4 = *(const float4*)ww;
        float bq[4] = {b4.x, b4.y, b4.z, b4.w};
        float wq[4] = {w4.x, w4.y, w4.z, w4.w};
        float local = 0.f;
        #pragma unroll
        for (int reg = 0; reg < 4; ++reg) {
            float hid = 0.25f * sn[reg] + bq[reg];
            hid = (hid > 0.f) ? hid : expm1f(hid);
            local = fmaf(hid, wq[reg], local);
        }
        local += __shfl_xor(local, 16);   // quad0+quad1 (2/3 duplicate)
        if (lane == 0) atomicAdd(&out[r], local);
    }
}

// ---------------------------------------------------------------------------
extern "C" void kernel_launch(void* const* d_in, const int* in_sizes, int n_in,
                              void* d_out, int out_size, void* d_ws, size_t ws_size,
                              hipStream_t stream)
{
    const float* agent_qs      = (const float*)d_in[0];
    const float* states        = (const float*)d_in[1];
    const float* hidden_states = (const float*)d_in[2];
    const float* uncertainty   = (const float*)d_in[3];
    const float* W_gat         = (const float*)d_in[4];
    const float* att_a         = (const float*)d_in[5];
    const float* w1s_W         = (const float*)d_in[6];
    const float* w1s_b         = (const float*)d_in[7];
    const float* b1_W          = (const float*)d_in[8];
    const float* b1_b          = (const float*)d_in[9];
    const float* wf_W          = (const float*)d_in[10];
    const float* wf_b          = (const float*)d_in[11];
    const float* V1_W          = (const float*)d_in[12];
    const float* V1_b          = (const float*)d_in[13];
    const float* V2_W          = (const float*)d_in[14];
    const float* V2_b          = (const float*)d_in[15];

    char* w = (char*)d_ws;
    unsigned short* w1sTf   = (unsigned short*)w;  w += (size_t)524288 * 2;
    unsigned short* WgTf    = (unsigned short*)w;  w += (size_t)9216 * 2;
    unsigned short* g_bf    = (unsigned short*)w;  w += (size_t)8388608 * 2;
    float* b1v              = (float*)w;           w += (size_t)131072 * 4;
    float* wfv              = (float*)w;           w += (size_t)131072 * 4;
    float* out              = (float*)d_out;

    k0_prep<<<321, 256, 0, stream>>>(w1s_W, W_gat, att_a, states,
                                     b1_W, b1_b, wf_W, wf_b, V1_W, V1_b,
                                     V2_W, V2_b, w1sTf, WgTf, b1v, wfv, out);

    k1_gat<<<1024, 256, 0, stream>>>(hidden_states, WgTf, g_bf);

    dim3 gmix(256, 4);
    k2_mix<<<gmix, 256, 0, stream>>>(states, w1sTf, g_bf, agent_qs, uncertainty,
                                     w1s_W, w1s_b, b1v, wfv, out);
}